// Round 18
// baseline (46.299 us; speedup 1.0000x reference)
//
#include <hip/hip_runtime.h>

#define NPERS 64
#define NJOINT 15
#define NDEPTH 128
#define BIGF 100000.0f
#define EPSF 1e-8f
#define INFF 3.0e38f

// DIAGNOSTIC ROUND: main q-loop executed TWICE (pass 1 kept alive, pass 2
// produces the output, numerically identical). dur(2x) - dur(1x) = marginal
// loop cost -> resolves the 3x model-vs-measurement gap (R8/R12/R13/R16/R17
// all converge to 27-33us while the LDS+VALU model says ~10us).
__global__ __launch_bounds__(256, 4)
void pose_match_kernel(
    const float* __restrict__ poses_3d,   // (B,NP,NJ,ND,3)
    const float* __restrict__ p2d,        // (B,NP,NJ,2)
    const float* __restrict__ vis,        // (B,NP,NJ)
    const int*   __restrict__ nper,       // (B,)
    const float* __restrict__ Rm,         // (B,3,3)
    const float* __restrict__ Tm,         // (B,3)
    const float* __restrict__ fm,         // (B,2)
    const float* __restrict__ cm,         // (B,2)
    const float* __restrict__ iw_,        // (B,)
    const float* __restrict__ ih_,        // (B,)
    float* __restrict__ out)              // (B,NP,NJ,ND)
{
    const int b    = blockIdx.x >> 6;     // 64 blocks/batch: 32 pp x 2 dh
    const int rem  = blockIdx.x & 63;
    const int pp   = rem >> 1;
    const int dh   = rem & 1;
    const int p0   = pp * 2;
    const int tid  = threadIdx.x;
    const int lane = tid & 63;
    const int d    = dh * 64 + lane;      // this thread's depth bin
    const int wvs  = __builtin_amdgcn_readfirstlane(tid >> 6);   // 0..3

    __shared__ float4 sq[NPERS][NJOINT];  // {vis, rx, ry, _}  (epilogue)
    __shared__ float4 sco2[NJOINT][48];   // [j][q*3/4]: (w,wx,wy) per q
    __shared__ float  sc_c[NPERS];        // c term per q
    __shared__ float  bvred[4][2][64];    // [slice][person][lane]
    __shared__ int    bqred[4][2][64];

    // ---- stage raw candidate data ----
    for (int i = tid; i < NPERS * NJOINT; i += 256) {
        int q = i / NJOINT, j = i % NJOINT;
        float v  = vis[(b * NPERS + q) * NJOINT + j];
        float rx = p2d[((b * NPERS + q) * NJOINT + j) * 2 + 0];
        float ry = p2d[((b * NPERS + q) * NJOINT + j) * 2 + 1];
        sq[q][j] = make_float4(v, rx, ry, 0.0f);
    }
    __syncthreads();

    // ---- fold coefficients, transposed store [j][q*3] ----
    if (tid < NPERS) {
        const int q = tid;
        float vs = 0.0f, t2 = 0.0f;
        #pragma unroll
        for (int j = 0; j < NJOINT; ++j) {
            float4 s = sq[q][j];
            vs += s.x;
            t2 = fmaf(s.y * s.y + s.z * s.z, s.x, t2);
        }
        float inv = 1.0f / (vs + EPSF);
        #pragma unroll
        for (int j = 0; j < NJOINT; ++j) {
            float4 s = sq[q][j];
            float* row = (float*)&sco2[j][0];
            row[q * 3 + 0] = s.x * inv;
            row[q * 3 + 1] = 2.0f * s.x * s.y * inv;
            row[q * 3 + 2] = 2.0f * s.x * s.z * inv;
        }
        sc_c[q] = t2 * inv;
    }
    __syncthreads();

    // ---- camera params (wave-uniform scalars) ----
    const float R00 = Rm[b*9+0], R01 = Rm[b*9+1], R02 = Rm[b*9+2];
    const float R10 = Rm[b*9+3], R11 = Rm[b*9+4], R12 = Rm[b*9+5];
    const float R20 = Rm[b*9+6], R21 = Rm[b*9+7], R22 = Rm[b*9+8];
    const float T0 = Tm[b*3+0], T1 = Tm[b*3+1], T2 = Tm[b*3+2];
    const float fx = fm[b*2+0], fy = fm[b*2+1];
    const float cx = cm[b*2+0], cy = cm[b*2+1];
    const float iwm1 = iw_[b] - 1.0f;
    const float ihm1 = ih_[b] - 1.0f;
    const int   npv  = nper[b];

    const int q0  = wvs * 16;
    const int nvs = __builtin_amdgcn_readfirstlane(
                        min(max(npv - q0, 0), 16));

    const float* pA = poses_3d +
        ((size_t)(b * NPERS + p0    ) * NJOINT * NDEPTH + d) * 3;
    const float* pB = poses_3d +
        ((size_t)(b * NPERS + p0 + 1) * NJOINT * NDEPTH + d) * 3;

    float acc0[16], acc1[16];

    // The full main loop as a macro so it can be instantiated twice.
    // ZOFF is an opaque 0 in pass 2 -> defeats CSE of LDS loads/FMAs.
#define MAIN_LOOP(ZOFF)                                                       \
    {                                                                         \
        float cA0 = pA[0], cA1 = pA[1], cA2 = pA[2];                          \
        float cB0 = pB[0], cB1 = pB[1], cB2 = pB[2];                          \
        _Pragma("unroll 1")                                                   \
        for (int j = 0; j < NJOINT; ++j) {                                    \
            const int offn = ((j + 1 < NJOINT) ? (j + 1) : (NJOINT - 1))      \
                             * NDEPTH * 3;                                    \
            float nA0 = pA[offn + 0], nA1 = pA[offn + 1],                     \
                  nA2 = pA[offn + 2];                                         \
            float nB0 = pB[offn + 0], nB1 = pB[offn + 1],                     \
                  nB2 = pB[offn + 2];                                         \
            float X0, Y0, X1, Y1;                                             \
            {                                                                 \
                float a0 = cA0 - T0;                                          \
                float a1 = cA1 - T1;                                          \
                float a2 = cA2 - T2;                                          \
                float xc0 = R00 * a0 + R01 * a1 + R02 * a2;                   \
                float xc1 = R10 * a0 + R11 * a1 + R12 * a2;                   \
                float xc2 = R20 * a0 + R21 * a1 + R22 * a2;                   \
                float r   = __builtin_amdgcn_rcpf(xc2);                       \
                X0 = fmaf(fx * xc0, r, cx);                                   \
                Y0 = fmaf(fy * xc1, r, cy);                                   \
            }                                                                 \
            {                                                                 \
                float a0 = cB0 - T0;                                          \
                float a1 = cB1 - T1;                                          \
                float a2 = cB2 - T2;                                          \
                float xc0 = R00 * a0 + R01 * a1 + R02 * a2;                   \
                float xc1 = R10 * a0 + R11 * a1 + R12 * a2;                   \
                float xc2 = R20 * a0 + R21 * a1 + R22 * a2;                   \
                float r   = __builtin_amdgcn_rcpf(xc2);                       \
                X1 = fmaf(fx * xc0, r, cx);                                   \
                Y1 = fmaf(fy * xc1, r, cy);                                   \
            }                                                                 \
            _Pragma("unroll")                                                 \
            for (int g = 0; g < 4; ++g) {                                     \
                if (g * 4 < nvs) {                                            \
                    float4 r0 = sco2[j][wvs * 12 + g * 3 + 0 + (ZOFF)];       \
                    float4 r1 = sco2[j][wvs * 12 + g * 3 + 1 + (ZOFF)];       \
                    float4 r2 = sco2[j][wvs * 12 + g * 3 + 2 + (ZOFF)];       \
                    ACC1(0, r0.x, r0.y, r0.z)                                 \
                    ACC1(1, r0.w, r1.x, r1.y)                                 \
                    ACC1(2, r1.z, r1.w, r2.x)                                 \
                    ACC1(3, r2.y, r2.z, r2.w)                                 \
                }                                                             \
            }                                                                 \
            cA0 = nA0; cA1 = nA1; cA2 = nA2;                                  \
            cB0 = nB0; cB1 = nB1; cB2 = nB2;                                  \
        }                                                                     \
    }

#define ACC1(K, W, WX, WY)                                                    \
    {                                                                         \
        float u;                                                              \
        u = fmaf((W), X0, -(WX));                                             \
        acc0[g * 4 + K] = fmaf(X0, u, acc0[g * 4 + K]);                       \
        u = fmaf((W), Y0, -(WY));                                             \
        acc0[g * 4 + K] = fmaf(Y0, u, acc0[g * 4 + K]);                       \
        u = fmaf((W), X1, -(WX));                                             \
        acc1[g * 4 + K] = fmaf(X1, u, acc1[g * 4 + K]);                       \
        u = fmaf((W), Y1, -(WY));                                             \
        acc1[g * 4 + K] = fmaf(Y1, u, acc1[g * 4 + K]);                       \
    }

    if (nvs > 0) {
        // ---- PASS 1 (measured, result kept alive, then discarded) ----
        #pragma unroll
        for (int k = 0; k < 16; ++k) { acc0[k] = 0.0f; acc1[k] = 0.0f; }
        MAIN_LOOP(0)
        #pragma unroll
        for (int k = 0; k < 16; ++k)
            asm volatile("" :: "v"(acc0[k]), "v"(acc1[k]));
        __builtin_amdgcn_sched_barrier(0);
        asm volatile("" ::: "memory");

        // ---- PASS 2 (produces the output; opaque 0 defeats CSE) ----
        int zoff = 0;
        asm volatile("" : "+v"(zoff));
        #pragma unroll
        for (int k = 0; k < 16; ++k) { acc0[k] = 0.0f; acc1[k] = 0.0f; }
        MAIN_LOOP(zoff)
    } else {
        #pragma unroll
        for (int k = 0; k < 16; ++k) { acc0[k] = 0.0f; acc1[k] = 0.0f; }
    }
#undef ACC1
#undef MAIN_LOOP

    // ---- per-wave argmin (init == np.argmin over BIG-clamped array) ----
    float bv0, bv1;
    int   bq0, bq1;
    if (npv < NPERS) { bv0 = bv1 = BIGF; bq0 = bq1 = npv; }
    else             { bv0 = bv1 = INFF; bq0 = bq1 = 0;   }
    #pragma unroll
    for (int k = 0; k < 16; ++k) {
        if (k < nvs) {
            float cterm = sc_c[q0 + k];
            float d0 = acc0[k] + cterm;
            float d1 = acc1[k] + cterm;
            if (d0 < bv0) { bv0 = d0; bq0 = q0 + k; }
            if (d1 < bv1) { bv1 = d1; bq1 = q0 + k; }
        }
    }
    bvred[wvs][0][lane] = bv0;  bqred[wvs][0][lane] = bq0;
    bvred[wvs][1][lane] = bv1;  bqred[wvs][1][lane] = bq1;
    __syncthreads();

    // ---- waves 0,1 finish person 0,1: combine (value,q) + epilogue ----
#define EPILOGUE(PI, PPTR)                                                    \
    if (wvs == PI) {                                                          \
        float bestv = bvred[0][PI][lane];                                     \
        int   bestq = bqred[0][PI][lane];                                     \
        _Pragma("unroll")                                                     \
        for (int k = 1; k < 4; ++k) {                                         \
            float v  = bvred[k][PI][lane];                                    \
            int   qq = bqred[k][PI][lane];                                    \
            if (v < bestv || (v == bestv && qq < bestq)) {                    \
                bestv = v; bestq = qq;                                        \
            }                                                                 \
        }                                                                     \
        const int obase = ((b * NPERS + p0 + PI) * NJOINT) * NDEPTH + d;      \
        _Pragma("unroll")                                                     \
        for (int j = 0; j < NJOINT; ++j) {                                    \
            const int off = j * NDEPTH * 3;                                   \
            float a0 = PPTR[off + 0] - T0;                                    \
            float a1 = PPTR[off + 1] - T1;                                    \
            float a2 = PPTR[off + 2] - T2;                                    \
            float xc0 = R00 * a0 + R01 * a1 + R02 * a2;                       \
            float xc1 = R10 * a0 + R11 * a1 + R12 * a2;                       \
            float xc2 = R20 * a0 + R21 * a1 + R22 * a2;                       \
            float r   = __builtin_amdgcn_rcpf(xc2);                           \
            float xx  = fmaf(fx * xc0, r, cx);                                \
            float yy  = fmaf(fy * xc1, r, cy);                                \
            float4 v = sq[bestq][j];                                          \
            float dx = xx - v.y;                                              \
            float dy = yy - v.z;                                              \
            float md = fmaf(dx, dx, dy * dy);                                 \
            float sc = __expf(-md * (1.0f / 225.0f));                         \
            float inb = (xx >= 0.0f && yy >= 0.0f &&                          \
                         xx <= iwm1 && yy <= ihm1) ? 1.0f : 0.0f;             \
            out[obase + j * NDEPTH] = sc * inb * v.x;                         \
        }                                                                     \
    }

    EPILOGUE(0, pA)
    EPILOGUE(1, pB)
#undef EPILOGUE
}

extern "C" void kernel_launch(void* const* d_in, const int* in_sizes, int n_in,
                              void* d_out, int out_size, void* d_ws, size_t ws_size,
                              hipStream_t stream) {
    const float* poses_3d = (const float*)d_in[0];
    const float* p2d      = (const float*)d_in[1];
    const float* vis      = (const float*)d_in[2];
    const int*   nper     = (const int*)d_in[3];
    const float* Rm       = (const float*)d_in[4];
    const float* Tm       = (const float*)d_in[5];
    const float* fm       = (const float*)d_in[6];
    const float* cm       = (const float*)d_in[7];
    const float* iw       = (const float*)d_in[8];
    const float* ih       = (const float*)d_in[9];
    float* out = (float*)d_out;

    const int B = in_sizes[3];  // num_persons_ref has B elements
    dim3 grid(B * 64);          // (b, person-pair, depth-half)
    dim3 block(256);            // 4 waves = 4 contiguous q-slices
    pose_match_kernel<<<grid, block, 0, stream>>>(
        poses_3d, p2d, vis, nper, Rm, Tm, fm, cm, iw, ih, out);
}

// Round 19
// 33.463 us; speedup vs baseline: 1.3836x; 1.3836x over previous
//
#include <hip/hip_runtime.h>

#define NPERS 64
#define NJOINT 15
#define NDEPTH 128
#define BIGF 100000.0f
#define EPSF 1e-8f
#define INFF 3.0e38f

// R18 ablation: loop = ~17us (60%), fixed = ~13us (40%) of R17's 30us.
// This round removes the two measured redundancies:
//  1) projection was computed 4x per block (all 4 waves share the same
//     (p0,d) lanes!) INSIDE the loop -> now projected ONCE in the prologue
//     (wave w owns j = w, w+4, w+8, w+12; wave 3 also folds coefficients)
//     and shared via sxy[15][64] float4 in LDS; the loop reads one
//     lane-indexed ds_read_b128 per j instead of 12 global loads + 80 VALU.
//  2) the epilogue re-projected all 15 joints -> now reads the same sxy.
// Identical fp values/order as R17 (absmax lineage 9.5e-7).
__global__ __launch_bounds__(256, 4)
void pose_match_kernel(
    const float* __restrict__ poses_3d,   // (B,NP,NJ,ND,3)
    const float* __restrict__ p2d,        // (B,NP,NJ,2)
    const float* __restrict__ vis,        // (B,NP,NJ)
    const int*   __restrict__ nper,       // (B,)
    const float* __restrict__ Rm,         // (B,3,3)
    const float* __restrict__ Tm,         // (B,3)
    const float* __restrict__ fm,         // (B,2)
    const float* __restrict__ cm,         // (B,2)
    const float* __restrict__ iw_,        // (B,)
    const float* __restrict__ ih_,        // (B,)
    float* __restrict__ out)              // (B,NP,NJ,ND)
{
    const int b    = blockIdx.x >> 6;     // 64 blocks/batch: 32 pp x 2 dh
    const int rem  = blockIdx.x & 63;
    const int pp   = rem >> 1;
    const int dh   = rem & 1;
    const int p0   = pp * 2;
    const int tid  = threadIdx.x;
    const int lane = tid & 63;
    const int d    = dh * 64 + lane;      // this thread's depth bin
    const int wvs  = __builtin_amdgcn_readfirstlane(tid >> 6);   // 0..3

    __shared__ float4 sq[NPERS][NJOINT];  // {vis, rx, ry, _}  (epilogue)
    __shared__ float4 sco2[NJOINT][48];   // [j][q*3/4]: (w,wx,wy) per q
    __shared__ float  sc_c[NPERS];        // c term per q
    __shared__ float4 sxy[NJOINT][64];    // {X0,Y0,X1,Y1} per (j, lane)
    __shared__ float  bvred[4][2][64];    // [slice][person][lane]
    __shared__ int    bqred[4][2][64];

    // ---- stage raw candidate data ----
    for (int i = tid; i < NPERS * NJOINT; i += 256) {
        int q = i / NJOINT, j = i % NJOINT;
        float v  = vis[(b * NPERS + q) * NJOINT + j];
        float rx = p2d[((b * NPERS + q) * NJOINT + j) * 2 + 0];
        float ry = p2d[((b * NPERS + q) * NJOINT + j) * 2 + 1];
        sq[q][j] = make_float4(v, rx, ry, 0.0f);
    }
    __syncthreads();

    // ---- camera params (wave-uniform scalars) ----
    const float R00 = Rm[b*9+0], R01 = Rm[b*9+1], R02 = Rm[b*9+2];
    const float R10 = Rm[b*9+3], R11 = Rm[b*9+4], R12 = Rm[b*9+5];
    const float R20 = Rm[b*9+6], R21 = Rm[b*9+7], R22 = Rm[b*9+8];
    const float T0 = Tm[b*3+0], T1 = Tm[b*3+1], T2 = Tm[b*3+2];
    const float fx = fm[b*2+0], fy = fm[b*2+1];
    const float cx = cm[b*2+0], cy = cm[b*2+1];
    const float iwm1 = iw_[b] - 1.0f;
    const float ihm1 = ih_[b] - 1.0f;
    const int   npv  = nper[b];

    const float* pA = poses_3d +
        ((size_t)(b * NPERS + p0    ) * NJOINT * NDEPTH + d) * 3;
    const float* pB = poses_3d +
        ((size_t)(b * NPERS + p0 + 1) * NJOINT * NDEPTH + d) * 3;

    // ---- fold coefficients (wave 3 only; q = lane) ----
    if (wvs == 3) {
        const int q = lane;
        float vs = 0.0f, t2 = 0.0f;
        #pragma unroll
        for (int j = 0; j < NJOINT; ++j) {
            float4 s = sq[q][j];
            vs += s.x;
            t2 = fmaf(s.y * s.y + s.z * s.z, s.x, t2);
        }
        float inv = 1.0f / (vs + EPSF);
        #pragma unroll
        for (int j = 0; j < NJOINT; ++j) {
            float4 s = sq[q][j];
            float* row = (float*)&sco2[j][0];
            row[q * 3 + 0] = s.x * inv;
            row[q * 3 + 1] = 2.0f * s.x * s.y * inv;
            row[q * 3 + 2] = 2.0f * s.x * s.z * inv;
        }
        sc_c[q] = t2 * inv;
    }

    // ---- project each joint ONCE: wave w owns j = w, w+4, w+8, w+12 ----
    #pragma unroll
    for (int jj = 0; jj < 4; ++jj) {
        const int j = wvs + jj * 4;       // scalar
        if (j < NJOINT) {                 // scalar branch
            const int off = j * NDEPTH * 3;
            float X0, Y0, X1, Y1;
            {
                float a0 = pA[off + 0] - T0;
                float a1 = pA[off + 1] - T1;
                float a2 = pA[off + 2] - T2;
                float xc0 = R00 * a0 + R01 * a1 + R02 * a2;
                float xc1 = R10 * a0 + R11 * a1 + R12 * a2;
                float xc2 = R20 * a0 + R21 * a1 + R22 * a2;
                float r   = __builtin_amdgcn_rcpf(xc2);
                X0 = fmaf(fx * xc0, r, cx);
                Y0 = fmaf(fy * xc1, r, cy);
            }
            {
                float a0 = pB[off + 0] - T0;
                float a1 = pB[off + 1] - T1;
                float a2 = pB[off + 2] - T2;
                float xc0 = R00 * a0 + R01 * a1 + R02 * a2;
                float xc1 = R10 * a0 + R11 * a1 + R12 * a2;
                float xc2 = R20 * a0 + R21 * a1 + R22 * a2;
                float r   = __builtin_amdgcn_rcpf(xc2);
                X1 = fmaf(fx * xc0, r, cx);
                Y1 = fmaf(fy * xc1, r, cy);
            }
            sxy[j][lane] = make_float4(X0, Y0, X1, Y1);
        }
    }
    __syncthreads();

    // this wave's contiguous slice: q in [q0, q0+nvs), nvs provably scalar
    const int q0  = wvs * 16;
    const int nvs = __builtin_amdgcn_readfirstlane(
                        min(max(npv - q0, 0), 16));

    // ---- j-outer accumulation: 32 static accumulators ----
    float acc0[16], acc1[16];
    #pragma unroll
    for (int k = 0; k < 16; ++k) { acc0[k] = 0.0f; acc1[k] = 0.0f; }

    if (nvs > 0) {                         // scalar: idle waves skip all work
        #pragma unroll 1
        for (int j = 0; j < NJOINT; ++j) {
            // shared projection: one b128 read replaces 6 loads + ~80 VALU
            float4 xy = sxy[j][lane];
            const float X0 = xy.x, Y0 = xy.y, X1 = xy.z, Y1 = xy.w;

            #pragma unroll
            for (int g = 0; g < 4; ++g) {
                if (g * 4 < nvs) {         // scalar -> s_cbranch skips
                    float4 r0 = sco2[j][wvs * 12 + g * 3 + 0];
                    float4 r1 = sco2[j][wvs * 12 + g * 3 + 1];
                    float4 r2 = sco2[j][wvs * 12 + g * 3 + 2];
#define ACC1(K, W, WX, WY)                                                    \
                    {                                                         \
                        float u;                                              \
                        u = fmaf((W), X0, -(WX));                             \
                        acc0[g * 4 + K] = fmaf(X0, u, acc0[g * 4 + K]);       \
                        u = fmaf((W), Y0, -(WY));                             \
                        acc0[g * 4 + K] = fmaf(Y0, u, acc0[g * 4 + K]);       \
                        u = fmaf((W), X1, -(WX));                             \
                        acc1[g * 4 + K] = fmaf(X1, u, acc1[g * 4 + K]);       \
                        u = fmaf((W), Y1, -(WY));                             \
                        acc1[g * 4 + K] = fmaf(Y1, u, acc1[g * 4 + K]);       \
                    }
                    ACC1(0, r0.x, r0.y, r0.z)
                    ACC1(1, r0.w, r1.x, r1.y)
                    ACC1(2, r1.z, r1.w, r2.x)
                    ACC1(3, r2.y, r2.z, r2.w)
#undef ACC1
                }
            }
        }
    }

    // ---- per-wave argmin (init == np.argmin over BIG-clamped array) ----
    float bv0, bv1;
    int   bq0, bq1;
    if (npv < NPERS) { bv0 = bv1 = BIGF; bq0 = bq1 = npv; }
    else             { bv0 = bv1 = INFF; bq0 = bq1 = 0;   }
    #pragma unroll
    for (int k = 0; k < 16; ++k) {
        if (k < nvs) {                     // scalar branch
            float cterm = sc_c[q0 + k];
            float d0 = acc0[k] + cterm;
            float d1 = acc1[k] + cterm;
            if (d0 < bv0) { bv0 = d0; bq0 = q0 + k; }
            if (d1 < bv1) { bv1 = d1; bq1 = q0 + k; }
        }
    }
    bvred[wvs][0][lane] = bv0;  bqred[wvs][0][lane] = bq0;
    bvred[wvs][1][lane] = bv1;  bqred[wvs][1][lane] = bq1;
    __syncthreads();

    // ---- waves 0,1 finish person 0,1: combine (value,q) + epilogue.
    //      X/Y come from the shared sxy table (no reprojection). ----
#define EPILOGUE(PI)                                                          \
    if (wvs == PI) {                                                          \
        float bestv = bvred[0][PI][lane];                                     \
        int   bestq = bqred[0][PI][lane];                                     \
        _Pragma("unroll")                                                     \
        for (int k = 1; k < 4; ++k) {                                         \
            float v  = bvred[k][PI][lane];                                    \
            int   qq = bqred[k][PI][lane];                                    \
            if (v < bestv || (v == bestv && qq < bestq)) {                    \
                bestv = v; bestq = qq;                                        \
            }                                                                 \
        }                                                                     \
        const int obase = ((b * NPERS + p0 + PI) * NJOINT) * NDEPTH + d;      \
        _Pragma("unroll")                                                     \
        for (int j = 0; j < NJOINT; ++j) {                                    \
            float4 xy = sxy[j][lane];                                         \
            float xx = (PI == 0) ? xy.x : xy.z;                               \
            float yy = (PI == 0) ? xy.y : xy.w;                               \
            float4 v = sq[bestq][j];                                          \
            float dx = xx - v.y;                                              \
            float dy = yy - v.z;                                              \
            float md = fmaf(dx, dx, dy * dy);                                 \
            float sc = __expf(-md * (1.0f / 225.0f));                         \
            float inb = (xx >= 0.0f && yy >= 0.0f &&                          \
                         xx <= iwm1 && yy <= ihm1) ? 1.0f : 0.0f;             \
            out[obase + j * NDEPTH] = sc * inb * v.x;                         \
        }                                                                     \
    }

    EPILOGUE(0)
    EPILOGUE(1)
#undef EPILOGUE
}

extern "C" void kernel_launch(void* const* d_in, const int* in_sizes, int n_in,
                              void* d_out, int out_size, void* d_ws, size_t ws_size,
                              hipStream_t stream) {
    const float* poses_3d = (const float*)d_in[0];
    const float* p2d      = (const float*)d_in[1];
    const float* vis      = (const float*)d_in[2];
    const int*   nper     = (const int*)d_in[3];
    const float* Rm       = (const float*)d_in[4];
    const float* Tm       = (const float*)d_in[5];
    const float* fm       = (const float*)d_in[6];
    const float* cm       = (const float*)d_in[7];
    const float* iw       = (const float*)d_in[8];
    const float* ih       = (const float*)d_in[9];
    float* out = (float*)d_out;

    const int B = in_sizes[3];  // num_persons_ref has B elements
    dim3 grid(B * 64);          // (b, person-pair, depth-half)
    dim3 block(256);            // 4 waves = 4 contiguous q-slices
    pose_match_kernel<<<grid, block, 0, stream>>>(
        poses_3d, p2d, vis, nper, Rm, Tm, fm, cm, iw, ih, out);
}

// Round 20
// 29.604 us; speedup vs baseline: 1.5640x; 1.1303x over previous
//
#include <hip/hip_runtime.h>

#define NPERS 64
#define NJOINT 15
#define NDEPTH 128
#define BIGF 100000.0f
#define EPSF 1e-8f
#define INFF 3.0e38f

// R19 post-mortem: the g-gate SCALAR BRANCHES serialize the loop (3 ds_reads
// per basic block, no cross-block hoisting -> exposed LDS latency; R18's 16us
// marginal = 3x the throughput model). Critical-path blocks (npv=64) have
// nvs==16 -> all gates true. This round: branch-free unroll-2 fast path for
// nvs==16 (full pipelining, attacks exactly the blocks that set kernel time),
// R17 branchy path otherwise; fold on wave 3 (R19-proven); epilogue split
// over all 4 waves (person x j-parity).
__global__ __launch_bounds__(256, 4)
void pose_match_kernel(
    const float* __restrict__ poses_3d,   // (B,NP,NJ,ND,3)
    const float* __restrict__ p2d,        // (B,NP,NJ,2)
    const float* __restrict__ vis,        // (B,NP,NJ)
    const int*   __restrict__ nper,       // (B,)
    const float* __restrict__ Rm,         // (B,3,3)
    const float* __restrict__ Tm,         // (B,3)
    const float* __restrict__ fm,         // (B,2)
    const float* __restrict__ cm,         // (B,2)
    const float* __restrict__ iw_,        // (B,)
    const float* __restrict__ ih_,        // (B,)
    float* __restrict__ out)              // (B,NP,NJ,ND)
{
    const int b    = blockIdx.x >> 6;     // 64 blocks/batch: 32 pp x 2 dh
    const int rem  = blockIdx.x & 63;
    const int pp   = rem >> 1;
    const int dh   = rem & 1;
    const int p0   = pp * 2;
    const int tid  = threadIdx.x;
    const int lane = tid & 63;
    const int d    = dh * 64 + lane;      // this thread's depth bin
    const int wvs  = __builtin_amdgcn_readfirstlane(tid >> 6);   // 0..3

    __shared__ float4 sq[NPERS][NJOINT];  // {vis, rx, ry, _}  (epilogue)
    __shared__ float4 sco2[NJOINT][48];   // [j][q*3/4]: (w,wx,wy) per q
    __shared__ float  sc_c[NPERS];        // c term per q
    __shared__ float  bvred[4][2][64];    // [slice][person][lane]
    __shared__ int    bqred[4][2][64];

    // ---- stage raw candidate data ----
    for (int i = tid; i < NPERS * NJOINT; i += 256) {
        int q = i / NJOINT, j = i % NJOINT;
        float v  = vis[(b * NPERS + q) * NJOINT + j];
        float rx = p2d[((b * NPERS + q) * NJOINT + j) * 2 + 0];
        float ry = p2d[((b * NPERS + q) * NJOINT + j) * 2 + 1];
        sq[q][j] = make_float4(v, rx, ry, 0.0f);
    }
    __syncthreads();

    // ---- fold coefficients on wave 3 (wave 0 owns the always-full slice;
    //      keep its prologue light) ----
    if (wvs == 3) {
        const int q = lane;
        float vs = 0.0f, t2 = 0.0f;
        #pragma unroll
        for (int j = 0; j < NJOINT; ++j) {
            float4 s = sq[q][j];
            vs += s.x;
            t2 = fmaf(s.y * s.y + s.z * s.z, s.x, t2);
        }
        float inv = 1.0f / (vs + EPSF);
        #pragma unroll
        for (int j = 0; j < NJOINT; ++j) {
            float4 s = sq[q][j];
            float* row = (float*)&sco2[j][0];
            row[q * 3 + 0] = s.x * inv;
            row[q * 3 + 1] = 2.0f * s.x * s.y * inv;
            row[q * 3 + 2] = 2.0f * s.x * s.z * inv;
        }
        sc_c[q] = t2 * inv;
    }
    __syncthreads();

    // ---- camera params (wave-uniform scalars) ----
    const float R00 = Rm[b*9+0], R01 = Rm[b*9+1], R02 = Rm[b*9+2];
    const float R10 = Rm[b*9+3], R11 = Rm[b*9+4], R12 = Rm[b*9+5];
    const float R20 = Rm[b*9+6], R21 = Rm[b*9+7], R22 = Rm[b*9+8];
    const float T0 = Tm[b*3+0], T1 = Tm[b*3+1], T2 = Tm[b*3+2];
    const float fx = fm[b*2+0], fy = fm[b*2+1];
    const float cx = cm[b*2+0], cy = cm[b*2+1];
    const float iwm1 = iw_[b] - 1.0f;
    const float ihm1 = ih_[b] - 1.0f;
    const int   npv  = nper[b];

    const int q0  = wvs * 16;
    const int nvs = __builtin_amdgcn_readfirstlane(
                        min(max(npv - q0, 0), 16));

    const float* pA = poses_3d +
        ((size_t)(b * NPERS + p0    ) * NJOINT * NDEPTH + d) * 3;
    const float* pB = poses_3d +
        ((size_t)(b * NPERS + p0 + 1) * NJOINT * NDEPTH + d) * 3;

    float acc0[16], acc1[16];
    #pragma unroll
    for (int k = 0; k < 16; ++k) { acc0[k] = 0.0f; acc1[k] = 0.0f; }

    // one j-step: project both persons, then accumulate GCOUNT 4-q groups
#define JSTEP(J, GCOUNT)                                                      \
    {                                                                         \
        const int off = (J) * NDEPTH * 3;                                     \
        float X0, Y0, X1, Y1;                                                 \
        {                                                                     \
            float a0 = pA[off + 0] - T0;                                      \
            float a1 = pA[off + 1] - T1;                                      \
            float a2 = pA[off + 2] - T2;                                      \
            float xc0 = R00 * a0 + R01 * a1 + R02 * a2;                       \
            float xc1 = R10 * a0 + R11 * a1 + R12 * a2;                       \
            float xc2 = R20 * a0 + R21 * a1 + R22 * a2;                       \
            float r   = __builtin_amdgcn_rcpf(xc2);                           \
            X0 = fmaf(fx * xc0, r, cx);                                       \
            Y0 = fmaf(fy * xc1, r, cy);                                       \
        }                                                                     \
        {                                                                     \
            float a0 = pB[off + 0] - T0;                                      \
            float a1 = pB[off + 1] - T1;                                      \
            float a2 = pB[off + 2] - T2;                                      \
            float xc0 = R00 * a0 + R01 * a1 + R02 * a2;                       \
            float xc1 = R10 * a0 + R11 * a1 + R12 * a2;                       \
            float xc2 = R20 * a0 + R21 * a1 + R22 * a2;                       \
            float r   = __builtin_amdgcn_rcpf(xc2);                           \
            X1 = fmaf(fx * xc0, r, cx);                                       \
            Y1 = fmaf(fy * xc1, r, cy);                                       \
        }                                                                     \
        _Pragma("unroll")                                                     \
        for (int g = 0; g < (GCOUNT); ++g) {                                  \
            float4 r0 = sco2[J][wvs * 12 + g * 3 + 0];                        \
            float4 r1 = sco2[J][wvs * 12 + g * 3 + 1];                        \
            float4 r2 = sco2[J][wvs * 12 + g * 3 + 2];                        \
            ACC1(0, r0.x, r0.y, r0.z)                                         \
            ACC1(1, r0.w, r1.x, r1.y)                                         \
            ACC1(2, r1.z, r1.w, r2.x)                                         \
            ACC1(3, r2.y, r2.z, r2.w)                                         \
        }                                                                     \
    }

#define ACC1(K, W, WX, WY)                                                    \
    {                                                                         \
        float u;                                                              \
        u = fmaf((W), X0, -(WX));                                             \
        acc0[g * 4 + K] = fmaf(X0, u, acc0[g * 4 + K]);                       \
        u = fmaf((W), Y0, -(WY));                                             \
        acc0[g * 4 + K] = fmaf(Y0, u, acc0[g * 4 + K]);                       \
        u = fmaf((W), X1, -(WX));                                             \
        acc1[g * 4 + K] = fmaf(X1, u, acc1[g * 4 + K]);                       \
        u = fmaf((W), Y1, -(WY));                                             \
        acc1[g * 4 + K] = fmaf(Y1, u, acc1[g * 4 + K]);                       \
    }

    if (nvs == 16) {
        // ---- FAST PATH (critical-path blocks): branch-free, unroll 2 ----
        #pragma unroll 2
        for (int j = 0; j < NJOINT; ++j) {
            JSTEP(j, 4)
        }
    } else if (nvs > 0) {
        // ---- partial slice: off the critical path; branchy is fine ----
        #pragma unroll 1
        for (int j = 0; j < NJOINT; ++j) {
            const int ng = (nvs + 3) >> 2;            // scalar 1..4
            if (ng == 4)      { JSTEP(j, 4) }
            else if (ng == 3) { JSTEP(j, 3) }
            else if (ng == 2) { JSTEP(j, 2) }
            else              { JSTEP(j, 1) }
        }
    }
#undef ACC1
#undef JSTEP

    // ---- per-wave argmin (init == np.argmin over BIG-clamped array) ----
    float bv0, bv1;
    int   bq0, bq1;
    if (npv < NPERS) { bv0 = bv1 = BIGF; bq0 = bq1 = npv; }
    else             { bv0 = bv1 = INFF; bq0 = bq1 = 0;   }
    #pragma unroll
    for (int k = 0; k < 16; ++k) {
        if (k < nvs) {                     // scalar branch
            float cterm = sc_c[q0 + k];
            float d0 = acc0[k] + cterm;
            float d1 = acc1[k] + cterm;
            if (d0 < bv0) { bv0 = d0; bq0 = q0 + k; }
            if (d1 < bv1) { bv1 = d1; bq1 = q0 + k; }
        }
    }
    bvred[wvs][0][lane] = bv0;  bqred[wvs][0][lane] = bq0;
    bvred[wvs][1][lane] = bv1;  bqred[wvs][1][lane] = bq1;
    __syncthreads();

    // ---- epilogue split over ALL 4 waves: wave = person*2 + j-parity ----
#define EPILOGUE(PI, PAR, PPTR)                                               \
    if (wvs == (PI) * 2 + (PAR)) {                                            \
        float bestv = bvred[0][PI][lane];                                     \
        int   bestq = bqred[0][PI][lane];                                     \
        _Pragma("unroll")                                                     \
        for (int k = 1; k < 4; ++k) {                                         \
            float v  = bvred[k][PI][lane];                                    \
            int   qq = bqred[k][PI][lane];                                    \
            if (v < bestv || (v == bestv && qq < bestq)) {                    \
                bestv = v; bestq = qq;                                        \
            }                                                                 \
        }                                                                     \
        const int obase = ((b * NPERS + p0 + PI) * NJOINT) * NDEPTH + d;      \
        _Pragma("unroll")                                                     \
        for (int j = (PAR); j < NJOINT; j += 2) {                             \
            const int off = j * NDEPTH * 3;                                   \
            float a0 = PPTR[off + 0] - T0;                                    \
            float a1 = PPTR[off + 1] - T1;                                    \
            float a2 = PPTR[off + 2] - T2;                                    \
            float xc0 = R00 * a0 + R01 * a1 + R02 * a2;                       \
            float xc1 = R10 * a0 + R11 * a1 + R12 * a2;                       \
            float xc2 = R20 * a0 + R21 * a1 + R22 * a2;                       \
            float r   = __builtin_amdgcn_rcpf(xc2);                           \
            float xx  = fmaf(fx * xc0, r, cx);                                \
            float yy  = fmaf(fy * xc1, r, cy);                                \
            float4 v = sq[bestq][j];                                          \
            float dx = xx - v.y;                                              \
            float dy = yy - v.z;                                              \
            float md = fmaf(dx, dx, dy * dy);                                 \
            float sc = __expf(-md * (1.0f / 225.0f));                         \
            float inb = (xx >= 0.0f && yy >= 0.0f &&                          \
                         xx <= iwm1 && yy <= ihm1) ? 1.0f : 0.0f;             \
            out[obase + j * NDEPTH] = sc * inb * v.x;                         \
        }                                                                     \
    }

    EPILOGUE(0, 0, pA)
    EPILOGUE(0, 1, pA)
    EPILOGUE(1, 0, pB)
    EPILOGUE(1, 1, pB)
#undef EPILOGUE
}

extern "C" void kernel_launch(void* const* d_in, const int* in_sizes, int n_in,
                              void* d_out, int out_size, void* d_ws, size_t ws_size,
                              hipStream_t stream) {
    const float* poses_3d = (const float*)d_in[0];
    const float* p2d      = (const float*)d_in[1];
    const float* vis      = (const float*)d_in[2];
    const int*   nper     = (const int*)d_in[3];
    const float* Rm       = (const float*)d_in[4];
    const float* Tm       = (const float*)d_in[5];
    const float* fm       = (const float*)d_in[6];
    const float* cm       = (const float*)d_in[7];
    const float* iw       = (const float*)d_in[8];
    const float* ih       = (const float*)d_in[9];
    float* out = (float*)d_out;

    const int B = in_sizes[3];  // num_persons_ref has B elements
    dim3 grid(B * 64);          // (b, person-pair, depth-half)
    dim3 block(256);            // 4 waves = 4 contiguous q-slices
    pose_match_kernel<<<grid, block, 0, stream>>>(
        poses_3d, p2d, vis, nper, Rm, Tm, fm, cm, iw, ih, out);
}